// Round 29
// baseline (268.100 us; speedup 1.0000x reference)
//
#include <hip/hip_runtime.h>
#include <hip/hip_bf16.h>
#include <cmath>

#define DIM 512
#define HID 256
#define ROWS_PB 32       // rows per block (100000 = 3125 * 32, no tail)
#define NCHUNK 16        // K chunks of 32
#define CB 16384         // B chunk bytes: 32k * 256c * 2B

typedef __attribute__((ext_vector_type(8))) short short8;
typedef __attribute__((ext_vector_type(4))) float f32x4;
typedef __attribute__((ext_vector_type(16))) float f32x16;
typedef __attribute__((ext_vector_type(4))) unsigned int u32x4;

__device__ __forceinline__ unsigned short f2bf(float f) {
  union { float f; unsigned u; } v; v.f = f;
  unsigned u = v.u;
  return (unsigned short)((u + 0x7FFFu + ((u >> 16) & 1u)) >> 16);
}

// LDS-only barrier (R22/R23-verified): waits ds ops, syncs waves, fences
// the scheduler; does NOT drain vmcnt — reg-destined global loads survive.
#define LGKM_BAR()                                        \
  do {                                                    \
    asm volatile("s_waitcnt lgkmcnt(0)" ::: "memory");    \
    __builtin_amdgcn_s_barrier();                         \
    __builtin_amdgcn_sched_barrier(0);                    \
  } while (0)

// Pre-swizzle W1 (fp32 [512,256] row-major) into bf16 MFMA fragment order:
// w1s[((k>>3)*HID + c)*8 + (k&7)]. K-chunk c (32 k's) is the contiguous
// 16 KB at byte offset c*16384 — a linear copy. Serves the 32x32x16 shape.
__global__ void w1_swz_kernel(const float* __restrict__ W1,
                              unsigned short* __restrict__ w1s) {
  int tid = blockIdx.x * blockDim.x + threadIdx.x;
  if (tid >= DIM * HID) return;
  int k = tid / HID;
  int c = tid - k * HID;
  w1s[(((k >> 3) * HID) + c) * 8 + (k & 7)] = f2bf(W1[tid]);
}

__device__ __forceinline__ short8 cvt8(const f32x4 p0, const f32x4 p1) {
  short8 r;
  r[0] = (short)f2bf(p0[0]); r[1] = (short)f2bf(p0[1]);
  r[2] = (short)f2bf(p0[2]); r[3] = (short)f2bf(p0[3]);
  r[4] = (short)f2bf(p1[0]); r[5] = (short)f2bf(p1[1]);
  r[6] = (short)f2bf(p1[2]); r[7] = (short)f2bf(p1[3]);
  return r;
}

// R27 (32x32x16, no Az, -45% LDS-port traffic vs R23) with compiler
// register-rationing defeated: the 8 B-fragment ds_reads are one inline-asm
// batch with named =&v outputs — 32 VGPRs FORCED live, one lgkm wait per
// chunk instead of 8 serialized load->wait->use chains (R27's VGPR=88
// symptom). LGKM-only barriers keep all global loads in flight.
__global__ __launch_bounds__(256, 2) void fa_main_kernel(
    const float* __restrict__ z1, const float* __restrict__ z2,
    const unsigned short* __restrict__ w1s,
    const float* __restrict__ bias1, const float* __restrict__ W2,
    const float* __restrict__ bias2, float* __restrict__ out, int n) {
  __shared__ char Bs[CB];        // 16 KB single buffer
  __shared__ float xs2[4][32];   // partial logits [(s*2+h)][row]

  const int t = threadIdx.x;
  const int w = t >> 6;
  const int l = t & 63;
  const int l31 = l & 31, lhi = l >> 5;
  const int s = w & 1;   // source
  const int h = w >> 1;  // col-half
  const int row0 = blockIdx.x * ROWS_PB;
  int myrow = row0 + l31;
  const bool rok = myrow < n;
  if (!rok) myrow = n - 1;
  const float* zz = s ? z2 : z1;
  // A stream (R15-verified layout): lane=row l31; chunk c, kslice ks ->
  // 8 consecutive fp32 at ap + c*32 + ks*16 (ap folds in lhi*8).
  const float* ap = zz + (size_t)myrow * DIM + (lhi << 3);
  const f32x4 zf4 = (f32x4){0.f, 0.f, 0.f, 0.f};

  // T14 B-staging: 16 KB/chunk = 4 x u32x4 per thread (wave-private regs).
  u32x4 breg0, breg1, breg2, breg3;
#define BLOAD(c)                                            \
  {                                                         \
    const u32x4* g = (const u32x4*)w1s + (c) * 1024 + t;    \
    breg0 = g[0];                                           \
    breg1 = g[256];                                         \
    breg2 = g[512];                                         \
    breg3 = g[768];                                         \
  }
#define BWRITE()                                            \
  {                                                         \
    u32x4* d = (u32x4*)Bs + t;                              \
    d[0] = breg0;                                           \
    d[256] = breg1;                                         \
    d[512] = breg2;                                         \
    d[768] = breg3;                                         \
  }
  // A-pipe: 2 slots x 4 f32x4 (chunks c, c+1), statically rotated.
  f32x4 sA[4], sB[4];
#define ALOAD(c, slot)                                      \
  {                                                         \
    const float* p = ap + ((c) << 5);                       \
    slot[0] = rok ? *(const f32x4*)(p) : zf4;               \
    slot[1] = rok ? *(const f32x4*)(p + 4) : zf4;           \
    slot[2] = rok ? *(const f32x4*)(p + 16) : zf4;          \
    slot[3] = rok ? *(const f32x4*)(p + 20) : zf4;          \
  }

  // ---- Prologue: B[0] + A(0),A(1); one full drain.
  BLOAD(0);
  ALOAD(0, sA);
  ALOAD(1, sB);
  BWRITE();
  __syncthreads();  // Bs[0] visible

  f32x16 acc[4];
#pragma unroll
  for (int g = 0; g < 4; ++g)
#pragma unroll
    for (int r = 0; r < 16; ++r) acc[g][r] = 0.f;

  // Per-lane LDS byte base for the B-fragment batch:
  // frag(ks,g) @ byte ((lhi*256 + h*128 + l31) * 16) + ks*8192 + g*512.
  const unsigned bsBase =
      (unsigned)(size_t)(void*)Bs +
      ((unsigned)(((lhi << 8) + (h << 7) + l31)) << 4);

  // ---- K-loop: continuous A-stream, LGKM-only barriers, asm-batched
  // B reads (forced registers), 8 MFMAs.
#pragma unroll
  for (int c = 0; c < NCHUNK; ++c) {
    if (c + 1 < NCHUNK) BLOAD(c + 1);  // L2 -> regs, survives barriers
    short8 af0, af1;
    if (c & 1) {
      af0 = cvt8(sB[0], sB[1]);
      af1 = cvt8(sB[2], sB[3]);
    } else {
      af0 = cvt8(sA[0], sA[1]);
      af1 = cvt8(sA[2], sA[3]);
    }
    if (c + 2 < NCHUNK) {  // refill the consumed slot (HBM, in flight)
      if (c & 1) ALOAD(c + 2, sB) else ALOAD(c + 2, sA);
    }
    __builtin_amdgcn_sched_barrier(0);
    // Batched B-fragment reads: 8x ds_read_b128, named forced outputs.
    short8 bf0, bf1, bf2, bf3, bf4, bf5, bf6, bf7;
    asm volatile(
        "ds_read_b128 %0, %8 offset:0\n\t"
        "ds_read_b128 %1, %8 offset:512\n\t"
        "ds_read_b128 %2, %8 offset:1024\n\t"
        "ds_read_b128 %3, %8 offset:1536\n\t"
        "ds_read_b128 %4, %8 offset:8192\n\t"
        "ds_read_b128 %5, %8 offset:8704\n\t"
        "ds_read_b128 %6, %8 offset:9216\n\t"
        "ds_read_b128 %7, %8 offset:9728"
        : "=&v"(bf0), "=&v"(bf1), "=&v"(bf2), "=&v"(bf3), "=&v"(bf4),
          "=&v"(bf5), "=&v"(bf6), "=&v"(bf7)
        : "v"(bsBase)
        : "memory");
    asm volatile("s_waitcnt lgkmcnt(0)" ::: "memory");
    __builtin_amdgcn_sched_barrier(0);  // rule #18: fence MFMAs below the wait
    acc[0] = __builtin_amdgcn_mfma_f32_32x32x16_bf16(af0, bf0, acc[0], 0, 0, 0);
    acc[1] = __builtin_amdgcn_mfma_f32_32x32x16_bf16(af0, bf1, acc[1], 0, 0, 0);
    acc[2] = __builtin_amdgcn_mfma_f32_32x32x16_bf16(af0, bf2, acc[2], 0, 0, 0);
    acc[3] = __builtin_amdgcn_mfma_f32_32x32x16_bf16(af0, bf3, acc[3], 0, 0, 0);
    acc[0] = __builtin_amdgcn_mfma_f32_32x32x16_bf16(af1, bf4, acc[0], 0, 0, 0);
    acc[1] = __builtin_amdgcn_mfma_f32_32x32x16_bf16(af1, bf5, acc[1], 0, 0, 0);
    acc[2] = __builtin_amdgcn_mfma_f32_32x32x16_bf16(af1, bf6, acc[2], 0, 0, 0);
    acc[3] = __builtin_amdgcn_mfma_f32_32x32x16_bf16(af1, bf7, acc[3], 0, 0, 0);
    LGKM_BAR();  // Bs reads retired; vmem stays in flight
    if (c + 1 < NCHUNK) BWRITE();  // ds_write; own vmcnt wait on breg
    LGKM_BAR();  // Bs writes visible block-wide
  }

  // ---- Logits (R15-verified). C/D (32x32): col = h*128 + g*32 + l31,
  // row = (r&3) + 8*(r>>2) + 4*lhi.
  float part[16];
#pragma unroll
  for (int r = 0; r < 16; ++r) part[r] = 0.f;
#pragma unroll
  for (int g = 0; g < 4; ++g) {
    const int cc = (h << 7) + (g << 5) + l31;
    const float w2v = W2[cc];
    const float b1v = bias1[cc];
#pragma unroll
    for (int r = 0; r < 16; ++r) {
      const float hh = acc[g][r] + b1v;
      part[r] += (hh > 0.f) ? hh * w2v : 0.f;
    }
  }
#pragma unroll
  for (int r = 0; r < 16; ++r) {
#pragma unroll
    for (int m = 1; m < 32; m <<= 1) part[r] += __shfl_xor(part[r], m, 64);
  }
  if (l31 == 0) {
#pragma unroll
    for (int r = 0; r < 16; ++r) {
      const int row = (r & 3) + ((r >> 2) << 3) + (lhi << 2);
      xs2[(s << 1) + h][row] = part[r];
    }
  }
  __syncthreads();

  // ---- Epilogue (R15-verified): wave w rows w*8..+8; lane l cols l*4 and
  // 256+l*4. z re-read from global — L2-hot — fp32 end-to-end.
#pragma unroll
  for (int j = 0; j < 8; ++j) {
    const int rl = (w << 3) + j;
    const int grow = row0 + rl;
    if (grow < n) {
      const float x = xs2[0][rl] + xs2[1][rl];
      const float y = xs2[2][rl] + xs2[3][rl];
      const float sx = 1.f / (1.f + __expf(y - x));  // b2 cancels
      const float sy = 1.f - sx;
      const size_t off = (size_t)grow * DIM + (l << 2);
#pragma unroll
      for (int half = 0; half < 2; ++half) {
        const size_t o = off + (half << 8);
        const f32x4 a4 = *(const f32x4*)(z1 + o);
        const f32x4 b4 = *(const f32x4*)(z2 + o);
        f32x4 ov;
        ov[0] = sx * a4[0] + sy * b4[0];
        ov[1] = sx * a4[1] + sy * b4[1];
        ov[2] = sx * a4[2] + sy * b4[2];
        ov[3] = sx * a4[3] + sy * b4[3];
        *(f32x4*)(out + o) = ov;
      }
    }
  }
#undef BLOAD
#undef BWRITE
#undef ALOAD
}

extern "C" void kernel_launch(void* const* d_in, const int* in_sizes, int n_in,
                              void* d_out, int out_size, void* d_ws,
                              size_t ws_size, hipStream_t stream) {
  const float* z1 = (const float*)d_in[0];
  const float* z2 = (const float*)d_in[1];
  const float* W1 = (const float*)d_in[2];
  const float* b1 = (const float*)d_in[3];
  const float* W2 = (const float*)d_in[4];
  const float* b2 = (const float*)d_in[5];
  float* out = (float*)d_out;
  const int n = in_sizes[0] / DIM;
  unsigned short* w1s = (unsigned short*)d_ws;  // 512*256*2 = 256 KB

  hipLaunchKernelGGL(w1_swz_kernel, dim3((DIM * HID + 255) / 256), dim3(256),
                     0, stream, W1, w1s);
  const int nwg = (n + ROWS_PB - 1) / ROWS_PB;
  hipLaunchKernelGGL(fa_main_kernel, dim3(nwg), dim3(256), 0, stream, z1, z2,
                     w1s, b1, W2, b2, out, n);
}

// Round 30
// 185.592 us; speedup vs baseline: 1.4446x; 1.4446x over previous
//
#include <hip/hip_runtime.h>
#include <hip/hip_bf16.h>
#include <cmath>

#define DIM 512
#define HID 256
#define ROWS_PB 32       // rows per block (100000 = 3125 * 32, no tail)
#define NCHUNK 16        // K chunks of 32
#define CB 16384         // B chunk bytes: 32k * 256c * 2B

typedef __attribute__((ext_vector_type(8))) short short8;
typedef __attribute__((ext_vector_type(4))) float f32x4;
typedef __attribute__((ext_vector_type(4))) unsigned int u32x4;

__device__ __forceinline__ unsigned short f2bf(float f) {
  union { float f; unsigned u; } v; v.f = f;
  unsigned u = v.u;
  return (unsigned short)((u + 0x7FFFu + ((u >> 16) & 1u)) >> 16);
}
__device__ __forceinline__ float bf2f(short h) {
  union { unsigned u; float f; } v;
  v.u = ((unsigned)(unsigned short)h) << 16;
  return v.f;
}

// LDS-only barrier (R22/R23-verified): waits ds ops, syncs waves, fences
// the scheduler; does NOT drain vmcnt — reg-destined global loads survive.
#define LGKM_BAR()                                        \
  do {                                                    \
    asm volatile("s_waitcnt lgkmcnt(0)" ::: "memory");    \
    __builtin_amdgcn_s_barrier();                         \
    __builtin_amdgcn_sched_barrier(0);                    \
  } while (0)

// Pre-swizzle W1 (fp32 [512,256] row-major) into bf16 MFMA fragment order:
// w1s[((k>>3)*HID + c)*8 + (k&7)]. K-chunk c (32 k's) is the contiguous
// 16 KB at byte offset c*16384 — a linear copy.
__global__ void w1_swz_kernel(const float* __restrict__ W1,
                              unsigned short* __restrict__ w1s) {
  int tid = blockIdx.x * blockDim.x + threadIdx.x;
  if (tid >= DIM * HID) return;
  int k = tid / HID;
  int c = tid - k * HID;
  w1s[(((k >> 3) * HID) + c) * 8 + (k & 7)] = f2bf(W1[tid]);
}

__device__ __forceinline__ short8 cvt8(const f32x4 p0, const f32x4 p1) {
  short8 r;
  r[0] = (short)f2bf(p0[0]); r[1] = (short)f2bf(p0[1]);
  r[2] = (short)f2bf(p0[2]); r[3] = (short)f2bf(p0[3]);
  r[4] = (short)f2bf(p1[0]); r[5] = (short)f2bf(p1[1]);
  r[6] = (short)f2bf(p1[2]); r[7] = (short)f2bf(p1[3]);
  return r;
}

__device__ __forceinline__ void wcombine(float wa, const short8 a, float wb,
                                         const short8 b, f32x4& o0, f32x4& o1) {
#pragma unroll
  for (int i = 0; i < 4; ++i) {
    o0[i] = wa * bf2f(a[i]) + wb * bf2f(b[i]);
    o1[i] = wa * bf2f(a[i + 4]) + wb * bf2f(b[i + 4]);
  }
}

// R23 — the verified best of this session (205 us dispatch / 183 overall):
// R13/R18 structure + A streamed THROUGH the K-loop + LGKM-only barriers.
// Per chunk the wave loads A(c+2) from HBM into a 2-slot register pipe,
// cvt's A(c) and ds_writes it to Az (for the epilogue). LGKM-only barriers
// keep those HBM loads in flight across chunk boundaries — the block
// issues HBM reads continuously instead of a front-loaded burst.
__global__ __launch_bounds__(256, 2) void fa_main_kernel(
    const float* __restrict__ z1, const float* __restrict__ z2,
    const unsigned short* __restrict__ w1s,
    const float* __restrict__ bias1, const float* __restrict__ W2,
    const float* __restrict__ bias2, float* __restrict__ out, int n) {
  // Az [src][chunk][tile][lane] short8 = 64 KB; Bs 16 KB single buffer
  // (xs aliases Bs after the K-loop). Total 80 KB -> 2 blocks/CU.
  __shared__ char smem[81920];
  short8* Az = (short8*)smem;
  char* Bs = smem + 65536;
  float* xs = (float*)(smem + 65536);  // [src][32 rows], post-K-loop only

  const int t = threadIdx.x;
  const int w = t >> 6;
  const int l = t & 63;
  const int l15 = l & 15, l16 = l >> 4;
  const int s = w & 1;    // source
  const int tl = w >> 1;  // row tile 0..1
  const int row0 = blockIdx.x * ROWS_PB;
  const int myrow = row0 + tl * 16 + l15;
  const bool rok = myrow < n;
  const float* zz = s ? z2 : z1;
  const float* ap = zz + (size_t)myrow * DIM + (l16 << 3);
  const f32x4 zf4 = (f32x4){0.f, 0.f, 0.f, 0.f};

  // T14 B-staging: 16 KB/chunk = 4 x u32x4 per thread (wave-private regs).
  u32x4 breg0, breg1, breg2, breg3;
#define BLOAD(c)                                            \
  {                                                         \
    const u32x4* g = (const u32x4*)w1s + (c) * 1024 + t;    \
    breg0 = g[0];                                           \
    breg1 = g[256];                                         \
    breg2 = g[512];                                         \
    breg3 = g[768];                                         \
  }
#define BWRITE()                                            \
  {                                                         \
    u32x4* d = (u32x4*)Bs + t;                              \
    d[0] = breg0;                                           \
    d[256] = breg1;                                         \
    d[512] = breg2;                                         \
    d[768] = breg3;                                         \
  }

  // ---- Prologue: B[0] + A(0),A(1) into the 2-slot pipe; one full drain.
  BLOAD(0);
  f32x4 paA0, paA1, paB0, paB1;  // slots: even chunks (A), odd chunks (B)
  paA0 = rok ? *(const f32x4*)(ap) : zf4;
  paA1 = rok ? *(const f32x4*)(ap + 4) : zf4;
  paB0 = rok ? *(const f32x4*)(ap + 32) : zf4;
  paB1 = rok ? *(const f32x4*)(ap + 36) : zf4;
  BWRITE();
  __syncthreads();  // Bs[0] visible (A(0),A(1) also landed — fine)

  f32x4 acc[16];
#pragma unroll
  for (int f = 0; f < 16; ++f) acc[f] = zf4;

  // ---- K-loop: continuous HBM A-stream + LDS-only barriers.
#pragma unroll
  for (int c = 0; c < NCHUNK; ++c) {
    if (c + 1 < NCHUNK) BLOAD(c + 1);  // L2 -> regs, survives barriers
    // A(c): cvt from this chunk's slot; park in Az for the epilogue.
    short8 af;
    if (c & 1)
      af = cvt8(paB0, paB1);
    else
      af = cvt8(paA0, paA1);
    Az[((s * NCHUNK + c) * 2 + tl) * 64 + l] = af;
    // A(c+2): refill the slot just consumed (HBM, ~2 chunk periods ahead).
    if (c + 2 < NCHUNK) {
      const float* apn = ap + ((c + 2) << 5);
      if (c & 1) {
        paB0 = rok ? *(const f32x4*)(apn) : zf4;
        paB1 = rok ? *(const f32x4*)(apn + 4) : zf4;
      } else {
        paA0 = rok ? *(const f32x4*)(apn) : zf4;
        paA1 = rok ? *(const f32x4*)(apn + 4) : zf4;
      }
    }
    __builtin_amdgcn_sched_barrier(0);
    // Batched B-fragment reads, then the MFMA cluster (R22-proven).
    const short8* bp = (const short8*)Bs + (l16 << 8) + l15;
    short8 bf[16];
#pragma unroll
    for (int f = 0; f < 16; ++f) bf[f] = bp[f << 4];
    __builtin_amdgcn_sched_barrier(0);
#pragma unroll
    for (int f = 0; f < 16; ++f)
      acc[f] =
          __builtin_amdgcn_mfma_f32_16x16x32_bf16(af, bf[f], acc[f], 0, 0, 0);
    LGKM_BAR();  // Bs reads + Az write retired; vmem stays in flight
    if (c + 1 < NCHUNK) BWRITE();  // ds_write; own vmcnt wait on breg
    LGKM_BAR();  // Bs writes visible block-wide
  }

  // ---- Logits. C/D: col = f*16+l15, row-in-tile = l16*4+r.
  float part[4] = {0.f, 0.f, 0.f, 0.f};
#pragma unroll
  for (int f = 0; f < 16; ++f) {
    const int cc = (f << 4) + l15;
    const float w2v = W2[cc];
    const float b1v = bias1[cc];
#pragma unroll
    for (int r = 0; r < 4; ++r) {
      const float hh = acc[f][r] + b1v;
      part[r] += (hh > 0.f) ? hh * w2v : 0.f;
    }
  }
#pragma unroll
  for (int r = 0; r < 4; ++r) {
#pragma unroll
    for (int m = 1; m < 16; m <<= 1) part[r] += __shfl_xor(part[r], m, 16);
  }
  if (l15 == 0) {
#pragma unroll
    for (int r = 0; r < 4; ++r)
      xs[s * ROWS_PB + tl * 16 + (l16 << 2) + r] = part[r];
  }
  __syncthreads();

  // ---- Epilogue: scores + output, entirely from Az (no HBM reads).
  const float x = xs[tl * 16 + l15];
  const float y = xs[ROWS_PB + tl * 16 + l15];
  const float sx = 1.f / (1.f + __expf(y - x));  // b2 cancels
  const float sy = 1.f - sx;
  float* orow = out + (size_t)myrow * DIM + (l16 << 3);
  if (rok) {
#pragma unroll
    for (int j = 0; j < 8; ++j) {
      const int cc = (s << 3) + j;  // this wave covers column chunks s*8..+8
      const short8 a0 = Az[((0 * NCHUNK + cc) * 2 + tl) * 64 + l];
      const short8 a1 = Az[((1 * NCHUNK + cc) * 2 + tl) * 64 + l];
      f32x4 o0, o1;
      wcombine(sx, a0, sy, a1, o0, o1);
      *(f32x4*)(orow + (cc << 5)) = o0;
      *(f32x4*)(orow + (cc << 5) + 4) = o1;
    }
  }
#undef BLOAD
#undef BWRITE
}

extern "C" void kernel_launch(void* const* d_in, const int* in_sizes, int n_in,
                              void* d_out, int out_size, void* d_ws,
                              size_t ws_size, hipStream_t stream) {
  const float* z1 = (const float*)d_in[0];
  const float* z2 = (const float*)d_in[1];
  const float* W1 = (const float*)d_in[2];
  const float* b1 = (const float*)d_in[3];
  const float* W2 = (const float*)d_in[4];
  const float* b2 = (const float*)d_in[5];
  float* out = (float*)d_out;
  const int n = in_sizes[0] / DIM;
  unsigned short* w1s = (unsigned short*)d_ws;  // 512*256*2 = 256 KB

  hipLaunchKernelGGL(w1_swz_kernel, dim3((DIM * HID + 255) / 256), dim3(256),
                     0, stream, W1, w1s);
  const int nwg = (n + ROWS_PB - 1) / ROWS_PB;
  hipLaunchKernelGGL(fa_main_kernel, dim3(nwg), dim3(256), 0, stream, z1, z2,
                     w1s, b1, W2, b2, out, n);
}